// Round 6
// baseline (721.052 us; speedup 1.0000x reference)
//
#include <hip/hip_runtime.h>

// Problem constants (N=1)
constexpr int W_ = 160;   // input W (x), output dim 1
constexpr int H_ = 192;   // input H (y), output dim 2
constexpr int D_ = 64;    // input D (z), output dim 4 (innermost)
constexpr int C_ = 32;
constexpr int HW_  = H_ * W_;          // 30720
constexpr int DHWi = D_ * HW_;         // 1966080
constexpr int CD   = C_ * D_;          // 2048

// R5 post-mortem: VGPR=36 proves the compiler fully re-serialized the gather
// (~192 load->wait->use round trips per wave-pass; 192 x ~550cy / 4 waves/SIMD
// x 40 generations ~= the measured 1.07M cycles). Every round since R2 hit this
// same wall: source-level "clusters" get interleaved by the register allocator.
// R6: ONE change vs R5 -- a compiler memory barrier (asm volatile "" memory)
// between the 32-load loop and the blend loop. Load results must be live across
// it => compiler is FORCED to emit 32 back-to-back global_load_dword + counted
// vmcnt before use. One round trip per hh iteration instead of ~32.
// Keep frozen: L2 phase schedule (FETCH 618->100 MB proven), direct f4 NT
// stores, zero barriers, 4 blocks/CU residency throttle.
constexpr int TW = 32, TH = 12, TD = 16;
constexpr int NWT = W_ / TW;             // 5
constexpr int NHT = H_ / TH;             // 16
constexpr int NDT = D_ / TD;             // 4
constexpr int QPP = NWT * NHT;           // 80 blocks per phase
constexpr int CPX = C_ / 8;              // 4 channels per XCD
constexpr int NPH = CPX * NDT;           // 16 phases per XCD
constexpr int LDS_BYTES = 36864;         // 36 KB -> exactly 4 blocks/CU (residency throttle)

typedef float f4_t __attribute__((ext_vector_type(4)));

__global__ void __launch_bounds__(256, 4)
affine_grid_sample_kernel(const float* __restrict__ inp,
                          const float* __restrict__ th,
                          float* __restrict__ out)
{
    extern __shared__ float smem[];      // residency throttle only (never touched)

    const int t   = threadIdx.x;
    const int bid = blockIdx.x;
    const int xcd = bid & 7;             // XCD id (dispatch round-robin)
    int r = bid >> 3;                    // 0..1279 within XCD, dispatch order
    const int phase = r / QPP;           // 0..15 slowest: one (c,dt) slab at a time
    const int q     = r - phase * QPP;
    const int c  = xcd * CPX + (phase >> 2);
    const int dt = phase & 3;            // dt fastest -> consecutive phases share z-halo
    const int hs = q / NWT;
    const int wt = q - hs * NWT;
    const int w0 = wt * TW, h0 = hs * TH, d0 = dt * TD;

    if (bid < 0) smem[t] = 0.0f;         // keep dynamic-LDS alloc live (never executes)

    const float th0=th[0], th1=th[1], th2 =th[2],  th3 =th[3];
    const float th4=th[4], th5=th[5], th6 =th[6],  th7 =th[7];
    const float th8=th[8], th9=th[9], th10=th[10], th11=th[11];

    const float* __restrict__ pc = inp + (size_t)c * DHWi;

    // lane map: wave = (wl:16) x (dq:4) -> full 64B store segments per wave.
    const int wl = t & 15;               // w within 16-group
    const int dq = (t >> 4) & 3;         // d-quad: owns d0+4dq .. d0+4dq+3
    const int wh = (t >> 6) & 1;         // w-half of the 32-wide tile
    const int hp = t >> 7;               // h parity (threads 128..255 take odd hh)
    const int w  = w0 + wh * 16 + wl;
    const float xx = fmaf((float)w, 2.0f / (W_ - 1), -1.0f);

    // per-thread z-constants for its 4 d's
    float kzx[4], kzy[4], kzz[4];
    #pragma unroll
    for (int k = 0; k < 4; ++k) {
        const int d = d0 + 4 * dq + k;
        const float zz = fmaf((float)d, 2.0f / (D_ - 1), -1.0f);
        kzx[k] = fmaf(th2,  zz, th3);
        kzy[k] = fmaf(th6,  zz, th7);
        kzz[k] = fmaf(th10, zz, th11);
    }

    float* const ob = out + ((size_t)w * H_ + h0) * CD + (size_t)c * D_ + d0 + 4 * dq;

    #pragma unroll 1
    for (int hh = hp; hh < TH; hh += 2) {
        const float yy = fmaf((float)(h0 + hh), 2.0f / (H_ - 1), -1.0f);

        // ---- compute all 4 points' offsets ----
        unsigned o[4][8];
        float u0a[4], u1a[4], v0a[4], v1a[4], s0a[4], s1a[4];
        #pragma unroll
        for (int k = 0; k < 4; ++k) {
            const float px = (fmaf(th0, xx, fmaf(th1, yy, kzx[k])) + 1.0f) * (0.5f * (W_ - 1));
            const float py = (fmaf(th4, xx, fmaf(th5, yy, kzy[k])) + 1.0f) * (0.5f * (H_ - 1));
            const float pz = (fmaf(th8, xx, fmaf(th9, yy, kzz[k])) + 1.0f) * (0.5f * (D_ - 1));
            const float fx = floorf(px), fy = floorf(py), fz = floorf(pz);
            const int ix0 = (int)fx, iy0 = (int)fy, iz0 = (int)fz;
            const int ix1 = ix0 + 1, iy1 = iy0 + 1, iz1 = iz0 + 1;
            const float wx = px - fx, wy = py - fy, wz = pz - fz;
            // zeros-padding: per-axis weight of any OOB corner is zeroed
            u0a[k] = (ix0 >= 0 && ix0 < W_) ? (1.0f - wx) : 0.0f;
            u1a[k] = (ix1 >= 0 && ix1 < W_) ? wx          : 0.0f;
            v0a[k] = (iy0 >= 0 && iy0 < H_) ? (1.0f - wy) : 0.0f;
            v1a[k] = (iy1 >= 0 && iy1 < H_) ? wy          : 0.0f;
            s0a[k] = (iz0 >= 0 && iz0 < D_) ? (1.0f - wz) : 0.0f;
            s1a[k] = (iz1 >= 0 && iz1 < D_) ? wz          : 0.0f;
            const int cx0 = min(max(ix0, 0), W_ - 1), cx1 = min(max(ix1, 0), W_ - 1);
            const int cy0 = min(max(iy0, 0), H_ - 1), cy1 = min(max(iy1, 0), H_ - 1);
            const int cz0 = min(max(iz0, 0), D_ - 1), cz1 = min(max(iz1, 0), D_ - 1);
            const unsigned o00 = (unsigned)(cz0 * HW_ + cy0 * W_);
            const unsigned o01 = (unsigned)(cz0 * HW_ + cy1 * W_);
            const unsigned o10 = (unsigned)(cz1 * HW_ + cy0 * W_);
            const unsigned o11 = (unsigned)(cz1 * HW_ + cy1 * W_);
            o[k][0] = o00 + (unsigned)cx0;
            o[k][1] = o00 + (unsigned)cx1;
            o[k][2] = o01 + (unsigned)cx0;
            o[k][3] = o01 + (unsigned)cx1;
            o[k][4] = o10 + (unsigned)cx0;
            o[k][5] = o10 + (unsigned)cx1;
            o[k][6] = o11 + (unsigned)cx0;
            o[k][7] = o11 + (unsigned)cx1;
        }

        // ---- issue ALL 32 loads as one batch ----
        float b[4][8];
        #pragma unroll
        for (int k = 0; k < 4; ++k)
            #pragma unroll
            for (int j = 0; j < 8; ++j)
                b[k][j] = pc[o[k][j]];

        // Compiler barrier: forces all 32 loads to be ISSUED before any blend
        // consumes them (results must be live across the clobber). This is the
        // anti-serialization hammer -- without it the register allocator
        // interleaves load->wait->use (VGPR=36 in R5, ~192 round trips/wave).
        asm volatile("" ::: "memory");

        // ---- blend + direct full-width store (wave covers 16 w x 64B) ----
        f4_t val;
        #pragma unroll
        for (int k = 0; k < 4; ++k) {
            const float r00 = u0a[k] * b[k][0] + u1a[k] * b[k][1];
            const float r01 = u0a[k] * b[k][2] + u1a[k] * b[k][3];
            const float r10 = u0a[k] * b[k][4] + u1a[k] * b[k][5];
            const float r11 = u0a[k] * b[k][6] + u1a[k] * b[k][7];
            const float e0 = v0a[k] * r00 + v1a[k] * r01;
            const float e1 = v0a[k] * r10 + v1a[k] * r11;
            val[k] = s0a[k] * e0 + s1a[k] * e1;
        }
        // output is write-once streaming: non-temporal
        __builtin_nontemporal_store(val, (f4_t*)(ob + (size_t)hh * CD));
    }
}

extern "C" void kernel_launch(void* const* d_in, const int* in_sizes, int n_in,
                              void* d_out, int out_size, void* d_ws, size_t ws_size,
                              hipStream_t stream)
{
    const float* inp = (const float*)d_in[0];   // [1,32,64,192,160] fp32
    const float* th  = (const float*)d_in[1];   // 12 fp32
    float* out = (float*)d_out;                 // [1,160,192,32,64] fp32

    hipLaunchKernelGGL(affine_grid_sample_kernel, dim3(8 * NPH * QPP), dim3(256),
                       LDS_BYTES, stream, inp, th, out);
}

// Round 7
// 632.960 us; speedup vs baseline: 1.1392x; 1.1392x over previous
//
#include <hip/hip_runtime.h>

// Problem constants (N=1)
constexpr int W_ = 160;   // input W (x), output dim 1
constexpr int H_ = 192;   // input H (y), output dim 2
constexpr int D_ = 64;    // input D (z), output dim 4 (innermost)
constexpr int C_ = 32;
constexpr int HW_  = H_ * W_;          // 30720
constexpr int DHWi = D_ * HW_;         // 1966080
constexpr int CD   = C_ * D_;          // 2048

// R6 post-mortem: asm("":::"memory") is DEFEATED by __restrict__ (noalias => the
// clobber can't touch *pc => loads sink back into uses; VGPR stayed 36). The
// batching experiment never ran. R7 runs it for real:
//  (a) mega-asm with ALL loaded values as "v" operands -> all results must be
//      simultaneously live in VGPRs at one point -> back-to-back load issue,
//      one vmcnt wait; + sched_barrier(0) so blends can't hoist above it.
//  (b) x-pair loads: the 8 taps are 4 rows x adjacent (x0,x0+1). One 8B load
//      per row at base e=clamp(ix0,0,W-2) (global_load_dwordx2, 4B-aligned;
//      edge parity handled by exact weight shuffle). 32 -> 16 scattered
//      instructions per point-group, address VALU halved.
// Keep frozen: L2 phase schedule (FETCH 618->100 MB proven), direct f4 NT
// stores, zero barriers, 4 blocks/CU residency throttle.
constexpr int TW = 32, TH = 12, TD = 16;
constexpr int NWT = W_ / TW;             // 5
constexpr int NHT = H_ / TH;             // 16
constexpr int NDT = D_ / TD;             // 4
constexpr int QPP = NWT * NHT;           // 80 blocks per phase
constexpr int CPX = C_ / 8;              // 4 channels per XCD
constexpr int NPH = CPX * NDT;           // 16 phases per XCD
constexpr int LDS_BYTES = 36864;         // 36 KB -> exactly 4 blocks/CU (residency throttle)

typedef float f4_t __attribute__((ext_vector_type(4)));
typedef float f2_t __attribute__((ext_vector_type(2)));

__global__ void __launch_bounds__(256, 4)
affine_grid_sample_kernel(const float* __restrict__ inp,
                          const float* __restrict__ th,
                          float* __restrict__ out)
{
    extern __shared__ float smem[];      // residency throttle only (never touched)

    const int t   = threadIdx.x;
    const int bid = blockIdx.x;
    const int xcd = bid & 7;             // XCD id (dispatch round-robin)
    int r = bid >> 3;                    // 0..1279 within XCD, dispatch order
    const int phase = r / QPP;           // 0..15 slowest: one (c,dt) slab at a time
    const int q     = r - phase * QPP;
    const int c  = xcd * CPX + (phase >> 2);
    const int dt = phase & 3;            // dt fastest -> consecutive phases share z-halo
    const int hs = q / NWT;
    const int wt = q - hs * NWT;
    const int w0 = wt * TW, h0 = hs * TH, d0 = dt * TD;

    if (bid < 0) smem[t] = 0.0f;         // keep dynamic-LDS alloc live (never executes)

    const float th0=th[0], th1=th[1], th2 =th[2],  th3 =th[3];
    const float th4=th[4], th5=th[5], th6 =th[6],  th7 =th[7];
    const float th8=th[8], th9=th[9], th10=th[10], th11=th[11];

    const float* __restrict__ pc = inp + (size_t)c * DHWi;

    // lane map: wave = (wl:16) x (dq:4) -> full 64B store segments per wave.
    const int wl = t & 15;               // w within 16-group
    const int dq = (t >> 4) & 3;         // d-quad: owns d0+4dq .. d0+4dq+3
    const int wh = (t >> 6) & 1;         // w-half of the 32-wide tile
    const int hp = t >> 7;               // h parity (threads 128..255 take odd hh)
    const int w  = w0 + wh * 16 + wl;
    const float xx = fmaf((float)w, 2.0f / (W_ - 1), -1.0f);

    // per-thread z-constants for its 4 d's
    float kzx[4], kzy[4], kzz[4];
    #pragma unroll
    for (int k = 0; k < 4; ++k) {
        const int d = d0 + 4 * dq + k;
        const float zz = fmaf((float)d, 2.0f / (D_ - 1), -1.0f);
        kzx[k] = fmaf(th2,  zz, th3);
        kzy[k] = fmaf(th6,  zz, th7);
        kzz[k] = fmaf(th10, zz, th11);
    }

    float* const ob = out + ((size_t)w * H_ + h0) * CD + (size_t)c * D_ + d0 + 4 * dq;

    #pragma unroll 1
    for (int hh = hp; hh < TH; hh += 2) {
        const float yy = fmaf((float)(h0 + hh), 2.0f / (H_ - 1), -1.0f);

        // ---- per point: 4 row offsets (x-pair base) + shuffled pair weights ----
        unsigned off[4][4];
        float wA[4], wB[4], v0a[4], v1a[4], s0a[4], s1a[4];
        #pragma unroll
        for (int k = 0; k < 4; ++k) {
            const float px = (fmaf(th0, xx, fmaf(th1, yy, kzx[k])) + 1.0f) * (0.5f * (W_ - 1));
            const float py = (fmaf(th4, xx, fmaf(th5, yy, kzy[k])) + 1.0f) * (0.5f * (H_ - 1));
            const float pz = (fmaf(th8, xx, fmaf(th9, yy, kzz[k])) + 1.0f) * (0.5f * (D_ - 1));
            const float fx = floorf(px), fy = floorf(py), fz = floorf(pz);
            const int ix0 = (int)fx, iy0 = (int)fy, iz0 = (int)fz;
            const float wx = px - fx, wy = py - fy, wz = pz - fz;
            // zeros-padding: per-axis weight of any OOB corner is zeroed
            const float u0r = ((unsigned)ix0       < (unsigned)W_) ? (1.0f - wx) : 0.0f;
            const float u1r = ((unsigned)(ix0 + 1) < (unsigned)W_) ? wx          : 0.0f;
            v0a[k] = ((unsigned)iy0       < (unsigned)H_) ? (1.0f - wy) : 0.0f;
            v1a[k] = ((unsigned)(iy0 + 1) < (unsigned)H_) ? wy          : 0.0f;
            s0a[k] = ((unsigned)iz0       < (unsigned)D_) ? (1.0f - wz) : 0.0f;
            s1a[k] = ((unsigned)(iz0 + 1) < (unsigned)D_) ? wz          : 0.0f;
            // pair P = (v[e], v[e+1]) with e = clamp(ix0, 0, W-2). Exact cases:
            //   ix0 in [0,W-2] : (wA,wB) = (u0r,u1r)           P=(x0,x1)
            //   ix0 == -1     : (u1r, 0)  -- x1 is v[0] = P.a
            //   ix0 == W-1    : (0, u0r)  -- x0 is v[W-1] = P.b
            //   else          : u0r=u1r=0 already
            float a = u0r, b = u1r;
            if (ix0 == -1)     { a = u1r; b = 0.0f; }
            if (ix0 == W_ - 1) { a = 0.0f; b = u0r; }
            wA[k] = a; wB[k] = b;
            const int e = min(max(ix0, 0), W_ - 2);
            const int cy0 = min(max(iy0,     0), H_ - 1);
            const int cy1 = min(max(iy0 + 1, 0), H_ - 1);
            const int cz0 = min(max(iz0,     0), D_ - 1);
            const int cz1 = min(max(iz0 + 1, 0), D_ - 1);
            off[k][0] = (unsigned)(cz0 * HW_ + cy0 * W_ + e);
            off[k][1] = (unsigned)(cz0 * HW_ + cy1 * W_ + e);
            off[k][2] = (unsigned)(cz1 * HW_ + cy0 * W_ + e);
            off[k][3] = (unsigned)(cz1 * HW_ + cy1 * W_ + e);
        }

        // ---- issue ALL 16 pair-loads as one batch ----
        f2_t P[4][4];
        #pragma unroll
        for (int k = 0; k < 4; ++k)
            #pragma unroll
            for (int j = 0; j < 4; ++j)
                __builtin_memcpy(&P[k][j], pc + off[k][j], 8);  // 8B load, 4B-aligned

        // Pin ALL results live at one point: forces back-to-back issue + a single
        // vmcnt wait. (Value-level pin -- cannot be defeated by noalias AA, unlike
        // R6's "memory" clobber.) sched_barrier stops blends hoisting above.
        asm volatile("" ::
            "v"(P[0][0]), "v"(P[0][1]), "v"(P[0][2]), "v"(P[0][3]),
            "v"(P[1][0]), "v"(P[1][1]), "v"(P[1][2]), "v"(P[1][3]),
            "v"(P[2][0]), "v"(P[2][1]), "v"(P[2][2]), "v"(P[2][3]),
            "v"(P[3][0]), "v"(P[3][1]), "v"(P[3][2]), "v"(P[3][3]));
        __builtin_amdgcn_sched_barrier(0);

        // ---- blend + direct full-width store (wave covers 16 w x 64B) ----
        f4_t val;
        #pragma unroll
        for (int k = 0; k < 4; ++k) {
            const float x00 = wA[k] * P[k][0][0] + wB[k] * P[k][0][1];
            const float x01 = wA[k] * P[k][1][0] + wB[k] * P[k][1][1];
            const float x10 = wA[k] * P[k][2][0] + wB[k] * P[k][2][1];
            const float x11 = wA[k] * P[k][3][0] + wB[k] * P[k][3][1];
            const float e0 = v0a[k] * x00 + v1a[k] * x01;
            const float e1 = v0a[k] * x10 + v1a[k] * x11;
            val[k] = s0a[k] * e0 + s1a[k] * e1;
        }
        // output is write-once streaming: non-temporal
        __builtin_nontemporal_store(val, (f4_t*)(ob + (size_t)hh * CD));
    }
}

extern "C" void kernel_launch(void* const* d_in, const int* in_sizes, int n_in,
                              void* d_out, int out_size, void* d_ws, size_t ws_size,
                              hipStream_t stream)
{
    const float* inp = (const float*)d_in[0];   // [1,32,64,192,160] fp32
    const float* th  = (const float*)d_in[1];   // 12 fp32
    float* out = (float*)d_out;                 // [1,160,192,32,64] fp32

    hipLaunchKernelGGL(affine_grid_sample_kernel, dim3(8 * NPH * QPP), dim3(256),
                       LDS_BYTES, stream, inp, th, out);
}